// Round 13
// baseline (1316.845 us; speedup 1.0000x reference)
//
#include <hip/hip_runtime.h>

typedef unsigned short u16;
typedef unsigned int   u32;
typedef unsigned long long u64;
typedef short    s8v  __attribute__((ext_vector_type(8)));   // 8 x bf16 bits
typedef float    f4v  __attribute__((ext_vector_type(4)));
typedef u64      ul2v __attribute__((ext_vector_type(2)));
typedef _Float16 h2v  __attribute__((ext_vector_type(2)));

#define DEV __device__ __forceinline__

DEV u16 f2bf(float f) {                       // fp32 -> bf16 (round-half-up)
  u32 u = __builtin_bit_cast(u32, f);
  return (u16)((u + 0x8000u) >> 16);
}
DEV float bf2f(u16 b) { u32 u = ((u32)b) << 16; return __builtin_bit_cast(float, u); }
DEV void splitbf(float f, u16& hi, u16& lo) { // f ~= hi + lo (bf16 pair)
  hi = f2bf(f);
  lo = f2bf(f - bf2f(hi));
}
DEV u16 f2h(float f) {                        // fp32 -> fp16 bits (RNE)
  _Float16 h = (_Float16)f;
  return __builtin_bit_cast(u16, h);
}
DEV float h2f(u16 b) { _Float16 h = __builtin_bit_cast(_Float16, b); return (float)h; }
DEV float fdot2u(u32 a, u32 b, float c) {     // half2 dot + acc (fp32)
#if __has_builtin(__builtin_amdgcn_fdot2)
  return __builtin_amdgcn_fdot2(__builtin_bit_cast(h2v, a),
                                __builtin_bit_cast(h2v, b), c, false);
#else
  h2v x = __builtin_bit_cast(h2v, a), y = __builtin_bit_cast(h2v, b);
  return c + (float)x[0]*(float)y[0] + (float)x[1]*(float)y[1];
#endif
}
DEV float sigm(float x) { return 1.f / (1.f + __expf(-x)); }
DEV f4v mfma16(s8v a, s8v b, f4v c) {
  return __builtin_amdgcn_mfma_f32_16x16x32_bf16(a, b, c, 0, 0, 0);
}
DEV u32 permpack(u32 a, u32 b) {  // {a[31:16], b[31:16]}: b in low half
#if __has_builtin(__builtin_amdgcn_perm)
  return __builtin_amdgcn_perm(a, b, 0x07060302u);
#else
  return (b >> 16) | (a & 0xffff0000u);
#endif
}
// load 8 contiguous fp32 and split into hi/lo bf16 MFMA fragments
DEV void split8(const float* __restrict__ ap, s8v& Ah, s8v& Al) {
  const float4 v0 = *(const float4*)ap;
  const float4 v1 = *(const float4*)(ap + 4);
  const float f[8] = {v0.x, v0.y, v0.z, v0.w, v1.x, v1.y, v1.z, v1.w};
  uint4 hh, ll;
  u32 hp[4], lp[4];
  #pragma unroll
  for (int i = 0; i < 4; ++i) {
    const u32 ua = __builtin_bit_cast(u32, f[2 * i]);
    const u32 ub = __builtin_bit_cast(u32, f[2 * i + 1]);
    const u32 ta = ua + 0x8000u, tb = ub + 0x8000u;
    hp[i] = permpack(tb, ta);                       // hi pair
    const float la = f[2 * i]     - __builtin_bit_cast(float, ta & 0xffff0000u);
    const float lb = f[2 * i + 1] - __builtin_bit_cast(float, tb & 0xffff0000u);
    lp[i] = permpack(__builtin_bit_cast(u32, lb) + 0x8000u,
                     __builtin_bit_cast(u32, la) + 0x8000u);
  }
  hh.x = hp[0]; hh.y = hp[1]; hh.z = hp[2]; hh.w = hp[3];
  ll.x = lp[0]; ll.y = lp[1]; ll.z = lp[2]; ll.w = lp[3];
  Ah = __builtin_bit_cast(s8v, hh);
  Al = __builtin_bit_cast(s8v, ll);
}

// ---------------- prep: split-bf16 weight conversions ----------------
// fcw K-dim is PERMUTED to pos-major (k' = pos*32 + oc) so conv2 can write
// out2 coalesced. GEMM is K-order-agnostic as long as A and B agree.
__global__ void prep_k(const float* __restrict__ w1, const float* __restrict__ w2,
                       const float* __restrict__ fcw, const float* __restrict__ wih,
                       const float* __restrict__ whh, const float* __restrict__ bih,
                       const float* __restrict__ bhh,
                       u16* __restrict__ w1h, u16* __restrict__ w1l,
                       u16* __restrict__ w2h, u16* __restrict__ w2l,
                       u16* __restrict__ fh,  u16* __restrict__ fl,
                       u16* __restrict__ ih,  u16* __restrict__ il,
                       u16* __restrict__ whhh, float* __restrict__ bsum) {
  const int i0 = blockIdx.x * 256 + threadIdx.x;
  const int st = gridDim.x * 256;
  for (int i = i0; i < 663552; i += st) {
    const int j = i / 2592, k2 = i - j * 2592;
    const int pos = k2 >> 5, oc = k2 & 31;          // k' = pos*32 + oc
    splitbf(fcw[j * 2592 + oc * 81 + pos], fh[i], fl[i]);
  }
  for (int i = i0; i < 262144; i += st) splitbf(wih[i], ih[i], il[i]);
  for (int i = i0; i < 262144; i += st) whhh[i] = f2h(whh[i]);
  for (int i = i0; i < 4096;   i += st) splitbf(w1[i], w1h[i], w1l[i]);
  for (int i = i0; i < 8192;   i += st) {
    const int oc = i >> 8, k = i & 255;
    const int ky = k >> 6, kx = (k >> 4) & 3, cc = k & 15;   // k = ky*64+kx*16+c
    splitbf(w2[((oc * 16 + cc) * 4 + ky) * 4 + kx], w2h[i], w2l[i]);
  }
  for (int i = i0; i < 1024; i += st) bsum[i] = bih[i] + bhh[i];
}

// ---- fused conv1+conv2: ONE 1024-thread block per image, 1 barrier ----
// Evidence synthesis (R10/R11/R12): R11's structure (direct fp32 reads +
// shared t1 + 1 barrier) is the best measured, but at 6 blocks/CU its
// 192 in-flight images/XCD (21 MB) thrash the 4 MB L2 and the 4x window
// overlap re-reads fall to HBM (~600us). Staged variants (R8/R12) fix the
// fetch but die on micro-phase barrier structure. Fix the CONTROL VARIABLE:
// fewer, bigger blocks. 1024 threads = 16 waves/block, 2 blocks/CU = 100%
// wave occupancy with only 64 images/XCD (7.2 MB ~= 1.8x L2) -> overlap
// mostly L2-served. conv1 weights are NOT register-preloaded (w1h/w1l is
// 8 KB L1-resident; per-k0 loads keep VGPR ~50, far under the 128-VGPR cap
// the compiler grants 1024-thread blocks — R4's spill lesson). Arithmetic
// identical to R12 (pos-major out2, permuted fcw).
__global__ __launch_bounds__(1024) void conv_k(const float* __restrict__ obs,
    const u16* __restrict__ w1h, const u16* __restrict__ w1l, const float* __restrict__ b1,
    const u16* __restrict__ w2h, const u16* __restrict__ w2l, const float* __restrict__ b2,
    u16* __restrict__ out2h, u16* __restrict__ out2l) {
  __shared__ __align__(16) u16 t1h[6400], t1l[6400];  // [400 pos][16 oc]
  const int tid = threadIdx.x, lane = tid & 63, wid = tid >> 6;  // wid 0..15
  const int l15 = lane & 15, kc = lane >> 4;
  const int n = blockIdx.x;
  const float bias1 = b1[l15];
  const float* img = obs + (u64)n * 28224;
  // conv1 (stride 4, 8x8): 25 chunks of 16 positions over 16 waves
  for (int ch = wid; ch < 25; ch += 16) {
    const int p = ch * 16 + l15;
    const int oy = p / 20, ox = p - oy * 20;
    const float* ab = img + oy * 336 + ox * 4;   // (4*oy)*84 + 4*ox
    f4v ahh = {0,0,0,0}, ahl = {0,0,0,0}, alh = {0,0,0,0};
    #pragma unroll
    for (int k0 = 0; k0 < 8; ++k0) {
      const int kb = k0 * 32 + kc * 8;           // k = c*64 + ky*8 + kx
      const int c = kb >> 6, ky = (kb >> 3) & 7;
      s8v Ah, Al;
      split8(ab + c * 7056 + ky * 84, Ah, Al);
      const int o1 = l15 * 256 + k0 * 32 + kc * 8;
      const s8v Bh = *(const s8v*)(w1h + o1);    // L1-hot, not reg-resident
      const s8v Bl = *(const s8v*)(w1l + o1);
      ahh = mfma16(Ah, Bh, ahh);
      ahl = mfma16(Ah, Bl, ahl);
      alh = mfma16(Al, Bh, alh);
    }
    const int pr0 = ch * 16 + kc * 4;
    #pragma unroll
    for (int r = 0; r < 4; ++r) {
      float v = fmaxf(ahh[r] + ahl[r] + alh[r] + bias1, 0.f);
      u16 hi, lo; splitbf(v, hi, lo);
      t1h[(pr0 + r) * 16 + l15] = hi;
      t1l[(pr0 + r) * 16 + l15] = lo;
    }
  }
  __syncthreads();                               // the only barrier
  // conv2 (stride 2, 4x4): 12 units (6 chunks x 2 oc-tiles), waves 0..11
  if (wid < 12) {
    const int ch = wid >> 1, ot = wid & 1;
    const float bb = ot ? b2[16 + l15] : b2[l15];
    const int p = ch * 16 + l15;
    const int pc = p < 81 ? p : 80;
    const int oy = pc / 9, ox = pc - oy * 9;
    const int base = (oy * 40 + ox * 2) * 16;
    f4v a0 = {0,0,0,0}, a1 = {0,0,0,0}, a2 = {0,0,0,0};
    #pragma unroll
    for (int k0 = 0; k0 < 8; ++k0) {
      const int kb = k0 * 32 + kc * 8;           // k = ky*64 + kx*16 + c
      const int ky = kb >> 6, kx = (kb >> 4) & 3, c0 = kb & 15;
      const int off = base + (ky * 20 + kx) * 16 + c0;
      s8v Ah = *(const s8v*)(t1h + off);
      s8v Al = *(const s8v*)(t1l + off);
      const int wo = (ot * 16 + l15) * 256 + k0 * 32 + kc * 8;
      s8v Bh = *(const s8v*)(w2h + wo);
      s8v Bl = *(const s8v*)(w2l + wo);
      a0 = mfma16(Ah, Bh, a0);
      a1 = mfma16(Ah, Bl, a1);
      a2 = mfma16(Al, Bh, a2);
    }
    const int oc = ot * 16 + l15;
    u16* dh = out2h + (u64)n * 2592;
    u16* dl = out2l + (u64)n * 2592;
    const int pr0 = ch * 16 + kc * 4;
    #pragma unroll
    for (int r = 0; r < 4; ++r) {
      const int pp = pr0 + r;
      if (pp < 81) {
        float v = fmaxf(a0[r] + a1[r] + a2[r] + bb, 0.f);
        u16 hi, lo; splitbf(v, hi, lo);
        dh[pp * 32 + oc] = hi;                   // pos-major: coalesced
        dl[pp * 32 + oc] = lo;
      }
    }
  }
}

// ------- split-bf16 GEMM: C = A(MxK) * B(NxK)^T, A~Ah+Al, B~Bh+Bl -------
// BM=BN=128, BK=32, 4 waves (2x2), each wave 64x64 via 4x4 16x16x32 MFMA
template <int RELU, int OSPLIT>
__global__ __launch_bounds__(256) void gemm3_k(const u16* __restrict__ Ah,
    const u16* __restrict__ Al, const u16* __restrict__ Bh, const u16* __restrict__ Bl,
    const float* __restrict__ bias, void* __restrict__ o1, void* __restrict__ o2,
    int M, int N, int K) {
  __shared__ __align__(16) u16 lAh[4096], lAl[4096];  // [128][32]
  __shared__ __align__(16) u16 lBh[4096], lBl[4096];  // [128][32]
  const int tid = threadIdx.x, lane = tid & 63, wid = tid >> 6;
  const int nb = N >> 7;
  const int bm = (int)blockIdx.x / nb, bn = (int)blockIdx.x % nb;
  const int m0 = bm << 7, n0 = bn << 7;
  const int wr = wid >> 1, wc = wid & 1;
  const int l15 = lane & 15, l4 = lane >> 4;
  f4v acc[4][4] = {};
  const int srow = tid >> 2;
  const int scol = (tid & 3) << 3;
  const u64 rA0 = (u64)(m0 + srow) * K + scol;
  const u64 rA1 = (u64)(m0 + 64 + srow) * K + scol;
  const u64 rB0 = (u64)(n0 + srow) * K + scol;
  const u64 rB1 = (u64)(n0 + 64 + srow) * K + scol;
  for (int k0 = 0; k0 < K; k0 += 32) {
    uint4 vah0 = *(const uint4*)(Ah + rA0 + k0);
    uint4 vah1 = *(const uint4*)(Ah + rA1 + k0);
    uint4 val0 = *(const uint4*)(Al + rA0 + k0);
    uint4 val1 = *(const uint4*)(Al + rA1 + k0);
    uint4 vbh0 = *(const uint4*)(Bh + rB0 + k0);
    uint4 vbh1 = *(const uint4*)(Bh + rB1 + k0);
    uint4 vbl0 = *(const uint4*)(Bl + rB0 + k0);
    uint4 vbl1 = *(const uint4*)(Bl + rB1 + k0);
    __syncthreads();
    ((uint4*)lAh)[tid] = vah0;  ((uint4*)lAh)[256 + tid] = vah1;
    ((uint4*)lAl)[tid] = val0;  ((uint4*)lAl)[256 + tid] = val1;
    ((uint4*)lBh)[tid] = vbh0;  ((uint4*)lBh)[256 + tid] = vbh1;
    ((uint4*)lBl)[tid] = vbl0;  ((uint4*)lBl)[256 + tid] = vbl1;
    __syncthreads();
    s8v afh[4], afl[4], bfh[4], bfl[4];
    #pragma unroll
    for (int a = 0; a < 4; ++a) {
      const int off = (wr * 64 + a * 16 + l15) * 32 + l4 * 8;
      afh[a] = *(const s8v*)(lAh + off);
      afl[a] = *(const s8v*)(lAl + off);
    }
    #pragma unroll
    for (int b = 0; b < 4; ++b) {
      const int off = (wc * 64 + b * 16 + l15) * 32 + l4 * 8;
      bfh[b] = *(const s8v*)(lBh + off);
      bfl[b] = *(const s8v*)(lBl + off);
    }
    #pragma unroll
    for (int a = 0; a < 4; ++a)
      #pragma unroll
      for (int b = 0; b < 4; ++b) {
        acc[a][b] = mfma16(afh[a], bfh[b], acc[a][b]);
        acc[a][b] = mfma16(afh[a], bfl[b], acc[a][b]);
        acc[a][b] = mfma16(afl[a], bfh[b], acc[a][b]);
      }
  }
  #pragma unroll
  for (int a = 0; a < 4; ++a) {
    const int mr = m0 + wr * 64 + a * 16 + l4 * 4;
    #pragma unroll
    for (int b = 0; b < 4; ++b) {
      const int col = n0 + wc * 64 + b * 16 + l15;
      const float bv = bias[col];
      #pragma unroll
      for (int r = 0; r < 4; ++r) {
        float v = acc[a][b][r] + bv;
        if (RELU) v = fmaxf(v, 0.f);
        const u64 idx = (u64)(mr + r) * N + col;
        if (OSPLIT) {
          u16 hi, lo; splitbf(v, hi, lo);
          ((u16*)o1)[idx] = hi;
          ((u16*)o2)[idx] = lo;
        } else {
          ((float*)o1)[idx] = v;
        }
      }
    }
  }
}

// ---------------- LSTM scan: 1 workgroup (1024 thr) per batch element ----
// thread (col=t&255, kq=t>>8) owns the K-QUARTER [kq*64, kq*64+64) of gate
// rows col (i), 256+col (f), 512+col (g) in VGPRs: 3 gates x 8 uint4 = 96
// VGPRs of weights — fits the 128-VGPR cap the compiler grants 1024-thread
// blocks. o-gate rows in LDS chunk-transposed [kp4][col] (0 bank conflicts
// measured). h carried as fp16 hi+lo pair (fp32-grade). K-quarter partials
// reduced via 12 KB LDS. kq is wave-uniform -> divergence-free.
__global__ __launch_bounds__(1024) void lstm_k(const float* __restrict__ pre,
    const float* __restrict__ mask, const float* __restrict__ h0,
    const float* __restrict__ c0, const u16* __restrict__ whh,
    float* __restrict__ hs) {
  __shared__ __align__(16) uint4 lds_o[32 * 256];   // [kp4][col], 128 KB
  __shared__ __align__(16) float4 lds_red[3 * 256]; // kq=1..3 partials, 12 KB
  __shared__ __align__(16) u32 lds_hh[128];         // h hi (fp16 pairs)
  __shared__ __align__(16) u32 lds_hl[128];         // h lo
  const int t = threadIdx.x, b = blockIdx.x;
  const int col = t & 255, kq = t >> 8;             // kq wave-uniform
  uint4 wi[8], wf[8], wg[8];
  {
    const u32* wb = (const u32*)whh;
    const uint4* pi_ = (const uint4*)(wb + (u64)col * 128) + kq * 8;
    const uint4* pf_ = (const uint4*)(wb + (u64)(256 + col) * 128) + kq * 8;
    const uint4* pg_ = (const uint4*)(wb + (u64)(512 + col) * 128) + kq * 8;
    #pragma unroll
    for (int q = 0; q < 8; ++q) {
      wi[q] = pi_[q]; wf[q] = pf_[q]; wg[q] = pg_[q];
    }
    const uint4* po_ = (const uint4*)(wb + (u64)(768 + col) * 128);
    #pragma unroll
    for (int j = 0; j < 8; ++j) {
      const int kp4 = kq * 8 + j;
      lds_o[kp4 * 256 + col] = po_[kp4];
    }
  }
  float c = 0.f;
  if (kq == 0) c = c0[b * 256 + col];
  if (t < 128) {
    float a0 = h0[b * 256 + 2 * t], a1 = h0[b * 256 + 2 * t + 1];
    u16 h0a = f2h(a0); u16 l0a = f2h(a0 - h2f(h0a));
    u16 h1a = f2h(a1); u16 l1a = f2h(a1 - h2f(h1a));
    lds_hh[t] = (u32)h0a | ((u32)h1a << 16);
    lds_hl[t] = (u32)l0a | ((u32)l1a << 16);
  }
  float npi = 0.f, npf = 0.f, npg = 0.f, npo = 0.f;
  if (kq == 0) {                                    // prefetch step-0 pre
    const float* pr = pre + (u64)b * 1024;
    npi = pr[col]; npf = pr[256 + col]; npg = pr[512 + col]; npo = pr[768 + col];
  }
  __syncthreads();
  for (int s = 0; s < 80; ++s) {
    float ai = npi, afv = npf, ag = npg, ao = npo;  // kq!=0: zeros (partials)
    #pragma unroll
    for (int j = 0; j < 8; ++j) {
      const int kk = kq * 8 + j;
      const uint4 ov = lds_o[kk * 256 + col];       // conflict-free
      const uint4 hh = ((const uint4*)lds_hh)[kk];  // broadcast
      const uint4 hl = ((const uint4*)lds_hl)[kk];  // broadcast
      ai  = fdot2u(wi[j].x, hh.x, ai);  ai  = fdot2u(wi[j].y, hh.y, ai);
      ai  = fdot2u(wi[j].z, hh.z, ai);  ai  = fdot2u(wi[j].w, hh.w, ai);
      ai  = fdot2u(wi[j].x, hl.x, ai);  ai  = fdot2u(wi[j].y, hl.y, ai);
      ai  = fdot2u(wi[j].z, hl.z, ai);  ai  = fdot2u(wi[j].w, hl.w, ai);
      afv = fdot2u(wf[j].x, hh.x, afv); afv = fdot2u(wf[j].y, hh.y, afv);
      afv = fdot2u(wf[j].z, hh.z, afv); afv = fdot2u(wf[j].w, hh.w, afv);
      afv = fdot2u(wf[j].x, hl.x, afv); afv = fdot2u(wf[j].y, hl.y, afv);
      afv = fdot2u(wf[j].z, hl.z, afv); afv = fdot2u(wf[j].w, hl.w, afv);
      ag  = fdot2u(wg[j].x, hh.x, ag);  ag  = fdot2u(wg[j].y, hh.y, ag);
      ag  = fdot2u(wg[j].z, hh.z, ag);  ag  = fdot2u(wg[j].w, hh.w, ag);
      ag  = fdot2u(wg[j].x, hl.x, ag);  ag  = fdot2u(wg[j].y, hl.y, ag);
      ag  = fdot2u(wg[j].z, hl.z, ag);  ag  = fdot2u(wg[j].w, hl.w, ag);
      ao  = fdot2u(ov.x, hh.x, ao);     ao  = fdot2u(ov.y, hh.y, ao);
      ao  = fdot2u(ov.z, hh.z, ao);     ao  = fdot2u(ov.w, hh.w, ao);
      ao  = fdot2u(ov.x, hl.x, ao);     ao  = fdot2u(ov.y, hl.y, ao);
      ao  = fdot2u(ov.z, hl.z, ao);     ao  = fdot2u(ov.w, hl.w, ao);
    }
    if (kq != 0) {
      float4 r; r.x = ai; r.y = afv; r.z = ag; r.w = ao;
      lds_red[(kq - 1) * 256 + col] = r;
    } else if (s + 1 < 80) {                        // prefetch next-step pre
      const float* pr = pre + (u64)((s + 1) * 128 + b) * 1024;
      npi = pr[col]; npf = pr[256 + col]; npg = pr[512 + col]; npo = pr[768 + col];
    }
    __syncthreads();
    if (kq == 0) {
      const float4 r1 = lds_red[col];
      const float4 r2 = lds_red[256 + col];
      const float4 r3 = lds_red[512 + col];
      ai += r1.x + r2.x + r3.x;
      afv += r1.y + r2.y + r3.y;
      ag += r1.z + r2.z + r3.z;
      ao += r1.w + r2.w + r3.w;
      const float m = mask[s * 128 + b];
      const float ig = sigm(ai), fg = sigm(afv), og = sigm(ao);
      const float gg = tanhf(ag);
      const float cn = fg * c + ig * gg;
      const float hn = og * tanhf(cn);
      hs[(u64)(s * 128 + b) * 256 + col] = hn;      // unmasked output
      c = cn * m;
      const float hm = hn * m;                      // masked carry
      u16 hhi = f2h(hm);
      u16 hlo = f2h(hm - h2f(hhi));
      ((u16*)lds_hh)[col] = hhi;
      ((u16*)lds_hl)[col] = hlo;
    }
    __syncthreads();
  }
}

// ---------------- heads: value, log-softmax, entropy, action gather -------
__global__ __launch_bounds__(256) void heads_k(const float* __restrict__ hs,
    const float* __restrict__ vw, const float* __restrict__ vb,
    const float* __restrict__ lw, const float* __restrict__ lb,
    const int* __restrict__ acts, float* __restrict__ out) {
  const int lane = threadIdx.x & 63, wid = threadIdx.x >> 6;
  const int row = blockIdx.x * 4 + wid;
  const float4 h4 = *(const float4*)(hs + (u64)row * 256 + lane * 4);
  float lj[18];
  #pragma unroll
  for (int j = 0; j < 18; ++j) {
    const float4 w4 = *(const float4*)(lw + j * 256 + lane * 4);
    float p = h4.x * w4.x + h4.y * w4.y + h4.z * w4.z + h4.w * w4.w;
    #pragma unroll
    for (int o = 32; o > 0; o >>= 1) p += __shfl_xor(p, o, 64);
    lj[j] = p + lb[j];
  }
  const float4 v4 = *(const float4*)(vw + lane * 4);
  float val = h4.x * v4.x + h4.y * v4.y + h4.z * v4.z + h4.w * v4.w;
  #pragma unroll
  for (int o = 32; o > 0; o >>= 1) val += __shfl_xor(val, o, 64);
  val += vb[0];
  float mx = lj[0];
  #pragma unroll
  for (int j = 1; j < 18; ++j) mx = fmaxf(mx, lj[j]);
  float sum = 0.f;
  #pragma unroll
  for (int j = 0; j < 18; ++j) sum += __expf(lj[j] - mx);
  const float ls = __logf(sum);
  const int a = acts[row];
  float tlp = 0.f, ent = 0.f;
  #pragma unroll
  for (int j = 0; j < 18; ++j) {
    const float lp = lj[j] - mx - ls;
    const float pj = __expf(lp);
    ent -= pj * lp;
    if (j == a) tlp = lp;
  }
  if (lane == 0) {
    out[row]         = tlp;
    out[10240 + row] = ent;
    out[20480 + row] = val;
  }
}

// ---------------- launch ----------------
extern "C" void kernel_launch(void* const* d_in, const int* in_sizes, int n_in,
                              void* d_out, int out_size, void* d_ws, size_t ws_size,
                              hipStream_t stream) {
  const float* obs  = (const float*)d_in[0];
  const float* mask = (const float*)d_in[1];
  const float* h0   = (const float*)d_in[2];
  const float* c0   = (const float*)d_in[3];
  const int*   acts = (const int*)d_in[4];
  const float* w1   = (const float*)d_in[5];
  const float* b1   = (const float*)d_in[6];
  const float* w2   = (const float*)d_in[7];
  const float* b2   = (const float*)d_in[8];
  const float* fcw  = (const float*)d_in[9];
  const float* fcb  = (const float*)d_in[10];
  const float* wih  = (const float*)d_in[11];
  const float* whh  = (const float*)d_in[12];
  const float* bih  = (const float*)d_in[13];
  const float* bhh  = (const float*)d_in[14];
  const float* vw   = (const float*)d_in[15];
  const float* vb   = (const float*)d_in[16];
  const float* lw   = (const float*)d_in[17];
  const float* lb   = (const float*)d_in[18];
  float* out = (float*)d_out;

  char* cur = (char*)d_ws;
  auto carve = [&](size_t bytes) {
    void* p = cur; cur += (bytes + 255) & ~(size_t)255; return p;
  };
  u16*   out2h = (u16*)carve(10240ULL * 2592 * 2);
  u16*   out2l = (u16*)carve(10240ULL * 2592 * 2);
  u16*   xh    = (u16*)carve(10240ULL * 256 * 2);
  u16*   xl    = (u16*)carve(10240ULL * 256 * 2);
  float* pre   = (float*)carve(10240ULL * 1024 * 4);
  float* hs    = (float*)carve(10240ULL * 256 * 4);
  u16*   w1h   = (u16*)carve(4096ULL * 2);
  u16*   w1l   = (u16*)carve(4096ULL * 2);
  u16*   w2h   = (u16*)carve(8192ULL * 2);
  u16*   w2l   = (u16*)carve(8192ULL * 2);
  u16*   fwh   = (u16*)carve(663552ULL * 2);
  u16*   fwl   = (u16*)carve(663552ULL * 2);
  u16*   iwh   = (u16*)carve(262144ULL * 2);
  u16*   iwl   = (u16*)carve(262144ULL * 2);
  u16*   whhh  = (u16*)carve(262144ULL * 2);
  float* bsum  = (float*)carve(1024ULL * 4);

  prep_k<<<512, 256, 0, stream>>>(w1, w2, fcw, wih, whh, bih, bhh,
                                  w1h, w1l, w2h, w2l, fwh, fwl, iwh, iwl, whhh, bsum);
  conv_k<<<10240, 1024, 0, stream>>>(obs, w1h, w1l, b1, w2h, w2l, b2, out2h, out2l);
  gemm3_k<1, 1><<<160, 256, 0, stream>>>(out2h, out2l, fwh, fwl, fcb, xh, xl,
                                         10240, 256, 2592);
  gemm3_k<0, 0><<<640, 256, 0, stream>>>(xh, xl, iwh, iwl, bsum, pre, nullptr,
                                         10240, 1024, 256);
  lstm_k<<<128, 1024, 0, stream>>>(pre, mask, h0, c0, whhh, hs);
  heads_k<<<2560, 256, 0, stream>>>(hs, vw, vb, lw, lb, acts, out);
}

// Round 14
// 812.975 us; speedup vs baseline: 1.6198x; 1.6198x over previous
//
#include <hip/hip_runtime.h>

typedef unsigned short u16;
typedef unsigned int   u32;
typedef unsigned long long u64;
typedef short    s8v  __attribute__((ext_vector_type(8)));   // 8 x bf16 bits
typedef float    f4v  __attribute__((ext_vector_type(4)));
typedef u64      ul2v __attribute__((ext_vector_type(2)));
typedef _Float16 h2v  __attribute__((ext_vector_type(2)));

#define DEV __device__ __forceinline__

DEV u16 f2bf(float f) {                       // fp32 -> bf16 (round-half-up)
  u32 u = __builtin_bit_cast(u32, f);
  return (u16)((u + 0x8000u) >> 16);
}
DEV float bf2f(u16 b) { u32 u = ((u32)b) << 16; return __builtin_bit_cast(float, u); }
DEV void splitbf(float f, u16& hi, u16& lo) { // f ~= hi + lo (bf16 pair)
  hi = f2bf(f);
  lo = f2bf(f - bf2f(hi));
}
DEV u16 f2h(float f) {                        // fp32 -> fp16 bits (RNE)
  _Float16 h = (_Float16)f;
  return __builtin_bit_cast(u16, h);
}
DEV float h2f(u16 b) { _Float16 h = __builtin_bit_cast(_Float16, b); return (float)h; }
DEV float fdot2u(u32 a, u32 b, float c) {     // half2 dot + acc (fp32)
#if __has_builtin(__builtin_amdgcn_fdot2)
  return __builtin_amdgcn_fdot2(__builtin_bit_cast(h2v, a),
                                __builtin_bit_cast(h2v, b), c, false);
#else
  h2v x = __builtin_bit_cast(h2v, a), y = __builtin_bit_cast(h2v, b);
  return c + (float)x[0]*(float)y[0] + (float)x[1]*(float)y[1];
#endif
}
DEV float sigm(float x) { return 1.f / (1.f + __expf(-x)); }
DEV f4v mfma16(s8v a, s8v b, f4v c) {
  return __builtin_amdgcn_mfma_f32_16x16x32_bf16(a, b, c, 0, 0, 0);
}
DEV u32 permpack(u32 a, u32 b) {  // {a[31:16], b[31:16]}: b in low half
#if __has_builtin(__builtin_amdgcn_perm)
  return __builtin_amdgcn_perm(a, b, 0x07060302u);
#else
  return (b >> 16) | (a & 0xffff0000u);
#endif
}
// split two pre-loaded float4 (8 contiguous fp32) into hi/lo bf16 fragments
DEV void split8r(float4 v0, float4 v1, s8v& Ah, s8v& Al) {
  const float f[8] = {v0.x, v0.y, v0.z, v0.w, v1.x, v1.y, v1.z, v1.w};
  uint4 hh, ll;
  u32 hp[4], lp[4];
  #pragma unroll
  for (int i = 0; i < 4; ++i) {
    const u32 ua = __builtin_bit_cast(u32, f[2 * i]);
    const u32 ub = __builtin_bit_cast(u32, f[2 * i + 1]);
    const u32 ta = ua + 0x8000u, tb = ub + 0x8000u;
    hp[i] = permpack(tb, ta);                       // hi pair
    const float la = f[2 * i]     - __builtin_bit_cast(float, ta & 0xffff0000u);
    const float lb = f[2 * i + 1] - __builtin_bit_cast(float, tb & 0xffff0000u);
    lp[i] = permpack(__builtin_bit_cast(u32, lb) + 0x8000u,
                     __builtin_bit_cast(u32, la) + 0x8000u);
  }
  hh.x = hp[0]; hh.y = hp[1]; hh.z = hp[2]; hh.w = hp[3];
  ll.x = lp[0]; ll.y = lp[1]; ll.z = lp[2]; ll.w = lp[3];
  Ah = __builtin_bit_cast(s8v, hh);
  Al = __builtin_bit_cast(s8v, ll);
}

// ---------------- prep: split-bf16 weight conversions ----------------
// fcw K-dim is PERMUTED to pos-major (k' = pos*32 + oc) so conv2 can write
// out2 coalesced. GEMM is K-order-agnostic as long as A and B agree.
__global__ void prep_k(const float* __restrict__ w1, const float* __restrict__ w2,
                       const float* __restrict__ fcw, const float* __restrict__ wih,
                       const float* __restrict__ whh, const float* __restrict__ bih,
                       const float* __restrict__ bhh,
                       u16* __restrict__ w1h, u16* __restrict__ w1l,
                       u16* __restrict__ w2h, u16* __restrict__ w2l,
                       u16* __restrict__ fh,  u16* __restrict__ fl,
                       u16* __restrict__ ih,  u16* __restrict__ il,
                       u16* __restrict__ whhh, float* __restrict__ bsum) {
  const int i0 = blockIdx.x * 256 + threadIdx.x;
  const int st = gridDim.x * 256;
  for (int i = i0; i < 663552; i += st) {
    const int j = i / 2592, k2 = i - j * 2592;
    const int pos = k2 >> 5, oc = k2 & 31;          // k' = pos*32 + oc
    splitbf(fcw[j * 2592 + oc * 81 + pos], fh[i], fl[i]);
  }
  for (int i = i0; i < 262144; i += st) splitbf(wih[i], ih[i], il[i]);
  for (int i = i0; i < 262144; i += st) whhh[i] = f2h(whh[i]);
  for (int i = i0; i < 4096;   i += st) splitbf(w1[i], w1h[i], w1l[i]);
  for (int i = i0; i < 8192;   i += st) {
    const int oc = i >> 8, k = i & 255;
    const int ky = k >> 6, kx = (k >> 4) & 3, cc = k & 15;   // k = ky*64+kx*16+c
    splitbf(w2[((oc * 16 + cc) * 4 + ky) * 4 + kx], w2h[i], w2l[i]);
  }
  for (int i = i0; i < 1024; i += st) bsum[i] = bih[i] + bhh[i];
}

// ---- fused conv1+conv2, R11 structure + DEEP LOAD PIPELINE (MLP fix) ----
// R13 counters resolved the conv mystery: occupancy 45%, VALU 21%, HBM 9%,
// and dur == hbm_bytes/achieved_bw — the kernel is limited by achieved
// bandwidth, which is limited by OUTSTANDING REQUESTS (need ~22 KB/CU in
// flight; VGPR-starved waves held ~4 loads). Every prior round traded
// occupancy against per-wave MLP along the same frontier. Break it:
// __launch_bounds__(256,2) -> 256-VGPR cap; conv1 issues ALL 16 fragment
// loads of a chunk into 64 registers FIRST (unrolled, statically indexed),
// then splits+MFMAs; conv1+conv2 weights reg-resident (reused storage).
// 8 waves/CU x 16 KB in flight = 128 KB/CU >> 22 KB needed -> BW/VALU-bound.
// Shared t1 [400][16] hi/lo (25.6 KB), ONE barrier, pos-major out2 writes.
__global__ __launch_bounds__(256, 2) void conv_k(const float* __restrict__ obs,
    const u16* __restrict__ w1h, const u16* __restrict__ w1l, const float* __restrict__ b1,
    const u16* __restrict__ w2h, const u16* __restrict__ w2l, const float* __restrict__ b2,
    u16* __restrict__ out2h, u16* __restrict__ out2l) {
  __shared__ __align__(16) u16 t1h[6400], t1l[6400];  // [400 pos][16 oc]
  const int tid = threadIdx.x, lane = tid & 63, wid = tid >> 6;
  const int l15 = lane & 15, kc = lane >> 4;
  const int n = blockIdx.x;
  s8v bw1h[8], bw1l[8];                          // conv1 weights (64 VGPR)
  #pragma unroll
  for (int k0 = 0; k0 < 8; ++k0) {
    const int o1 = l15 * 256 + k0 * 32 + kc * 8;
    bw1h[k0] = *(const s8v*)(w1h + o1);
    bw1l[k0] = *(const s8v*)(w1l + o1);
  }
  const float bias1 = b1[l15];
  const float* img = obs + (u64)n * 28224;
  // conv1 (stride 4, 8x8): 25 chunks of 16 positions, waves interleave
  for (int ch = wid; ch < 25; ch += 4) {
    const int p = ch * 16 + l15;
    const int oy = p / 20, ox = p - oy * 20;
    const float* ab = img + oy * 336 + ox * 4;   // (4*oy)*84 + 4*ox
    // phase 1: issue ALL 16 loads (64 VGPRs of results in flight)
    float4 ra[8], rb[8];
    #pragma unroll
    for (int k0 = 0; k0 < 8; ++k0) {
      const int kb = k0 * 32 + kc * 8;           // k = c*64 + ky*8 + kx
      const int c = kb >> 6, ky = (kb >> 3) & 7;
      const float* ap = ab + c * 7056 + ky * 84;
      ra[k0] = *(const float4*)ap;
      rb[k0] = *(const float4*)(ap + 4);
    }
    // phase 2: split + MFMA
    f4v ahh = {0,0,0,0}, ahl = {0,0,0,0}, alh = {0,0,0,0};
    #pragma unroll
    for (int k0 = 0; k0 < 8; ++k0) {
      s8v Ah, Al;
      split8r(ra[k0], rb[k0], Ah, Al);
      ahh = mfma16(Ah, bw1h[k0], ahh);
      ahl = mfma16(Ah, bw1l[k0], ahl);
      alh = mfma16(Al, bw1h[k0], alh);
    }
    const int pr0 = ch * 16 + kc * 4;
    #pragma unroll
    for (int r = 0; r < 4; ++r) {
      float v = fmaxf(ahh[r] + ahl[r] + alh[r] + bias1, 0.f);
      u16 hi, lo; splitbf(v, hi, lo);
      t1h[(pr0 + r) * 16 + l15] = hi;
      t1l[(pr0 + r) * 16 + l15] = lo;
    }
  }
  __syncthreads();                               // the only barrier
  // conv2 (stride 2, 4x4): 12 units (6 chunks x 2 oc-tiles) over 4 waves
  const float bb2a = b2[l15], bb2b = b2[16 + l15];
  for (int u = wid; u < 12; u += 4) {
    const int ch = u >> 1, ot = u & 1;           // ot fixed per wave-iter
    // preload this oc-tile's weights into registers (reuses dead bw1/ra/rb)
    s8v cw2h[8], cw2l[8];
    #pragma unroll
    for (int k0 = 0; k0 < 8; ++k0) {
      const int wo = (ot * 16 + l15) * 256 + k0 * 32 + kc * 8;
      cw2h[k0] = *(const s8v*)(w2h + wo);
      cw2l[k0] = *(const s8v*)(w2l + wo);
    }
    const int p = ch * 16 + l15;
    const int pc = p < 81 ? p : 80;
    const int oy = pc / 9, ox = pc - oy * 9;
    const int base = (oy * 40 + ox * 2) * 16;
    f4v a0 = {0,0,0,0}, a1 = {0,0,0,0}, a2 = {0,0,0,0};
    #pragma unroll
    for (int k0 = 0; k0 < 8; ++k0) {
      const int kb = k0 * 32 + kc * 8;           // k = ky*64 + kx*16 + c
      const int ky = kb >> 6, kx = (kb >> 4) & 3, c0 = kb & 15;
      const int off = base + (ky * 20 + kx) * 16 + c0;
      s8v Ah = *(const s8v*)(t1h + off);
      s8v Al = *(const s8v*)(t1l + off);
      a0 = mfma16(Ah, cw2h[k0], a0);
      a1 = mfma16(Ah, cw2l[k0], a1);
      a2 = mfma16(Al, cw2h[k0], a2);
    }
    const float bb = ot ? bb2b : bb2a;
    const int oc = ot * 16 + l15;
    u16* dh = out2h + (u64)n * 2592;
    u16* dl = out2l + (u64)n * 2592;
    const int pr0 = ch * 16 + kc * 4;
    #pragma unroll
    for (int r = 0; r < 4; ++r) {
      const int pp = pr0 + r;
      if (pp < 81) {
        float v = fmaxf(a0[r] + a1[r] + a2[r] + bb, 0.f);
        u16 hi, lo; splitbf(v, hi, lo);
        dh[pp * 32 + oc] = hi;                   // pos-major: coalesced
        dl[pp * 32 + oc] = lo;
      }
    }
  }
}

// ------- split-bf16 GEMM: C = A(MxK) * B(NxK)^T, A~Ah+Al, B~Bh+Bl -------
// BM=BN=128, BK=32, 4 waves (2x2), each wave 64x64 via 4x4 16x16x32 MFMA
template <int RELU, int OSPLIT>
__global__ __launch_bounds__(256) void gemm3_k(const u16* __restrict__ Ah,
    const u16* __restrict__ Al, const u16* __restrict__ Bh, const u16* __restrict__ Bl,
    const float* __restrict__ bias, void* __restrict__ o1, void* __restrict__ o2,
    int M, int N, int K) {
  __shared__ __align__(16) u16 lAh[4096], lAl[4096];  // [128][32]
  __shared__ __align__(16) u16 lBh[4096], lBl[4096];  // [128][32]
  const int tid = threadIdx.x, lane = tid & 63, wid = tid >> 6;
  const int nb = N >> 7;
  const int bm = (int)blockIdx.x / nb, bn = (int)blockIdx.x % nb;
  const int m0 = bm << 7, n0 = bn << 7;
  const int wr = wid >> 1, wc = wid & 1;
  const int l15 = lane & 15, l4 = lane >> 4;
  f4v acc[4][4] = {};
  const int srow = tid >> 2;
  const int scol = (tid & 3) << 3;
  const u64 rA0 = (u64)(m0 + srow) * K + scol;
  const u64 rA1 = (u64)(m0 + 64 + srow) * K + scol;
  const u64 rB0 = (u64)(n0 + srow) * K + scol;
  const u64 rB1 = (u64)(n0 + 64 + srow) * K + scol;
  for (int k0 = 0; k0 < K; k0 += 32) {
    uint4 vah0 = *(const uint4*)(Ah + rA0 + k0);
    uint4 vah1 = *(const uint4*)(Ah + rA1 + k0);
    uint4 val0 = *(const uint4*)(Al + rA0 + k0);
    uint4 val1 = *(const uint4*)(Al + rA1 + k0);
    uint4 vbh0 = *(const uint4*)(Bh + rB0 + k0);
    uint4 vbh1 = *(const uint4*)(Bh + rB1 + k0);
    uint4 vbl0 = *(const uint4*)(Bl + rB0 + k0);
    uint4 vbl1 = *(const uint4*)(Bl + rB1 + k0);
    __syncthreads();
    ((uint4*)lAh)[tid] = vah0;  ((uint4*)lAh)[256 + tid] = vah1;
    ((uint4*)lAl)[tid] = val0;  ((uint4*)lAl)[256 + tid] = val1;
    ((uint4*)lBh)[tid] = vbh0;  ((uint4*)lBh)[256 + tid] = vbh1;
    ((uint4*)lBl)[tid] = vbl0;  ((uint4*)lBl)[256 + tid] = vbl1;
    __syncthreads();
    s8v afh[4], afl[4], bfh[4], bfl[4];
    #pragma unroll
    for (int a = 0; a < 4; ++a) {
      const int off = (wr * 64 + a * 16 + l15) * 32 + l4 * 8;
      afh[a] = *(const s8v*)(lAh + off);
      afl[a] = *(const s8v*)(lAl + off);
    }
    #pragma unroll
    for (int b = 0; b < 4; ++b) {
      const int off = (wc * 64 + b * 16 + l15) * 32 + l4 * 8;
      bfh[b] = *(const s8v*)(lBh + off);
      bfl[b] = *(const s8v*)(lBl + off);
    }
    #pragma unroll
    for (int a = 0; a < 4; ++a)
      #pragma unroll
      for (int b = 0; b < 4; ++b) {
        acc[a][b] = mfma16(afh[a], bfh[b], acc[a][b]);
        acc[a][b] = mfma16(afh[a], bfl[b], acc[a][b]);
        acc[a][b] = mfma16(afl[a], bfh[b], acc[a][b]);
      }
  }
  #pragma unroll
  for (int a = 0; a < 4; ++a) {
    const int mr = m0 + wr * 64 + a * 16 + l4 * 4;
    #pragma unroll
    for (int b = 0; b < 4; ++b) {
      const int col = n0 + wc * 64 + b * 16 + l15;
      const float bv = bias[col];
      #pragma unroll
      for (int r = 0; r < 4; ++r) {
        float v = acc[a][b][r] + bv;
        if (RELU) v = fmaxf(v, 0.f);
        const u64 idx = (u64)(mr + r) * N + col;
        if (OSPLIT) {
          u16 hi, lo; splitbf(v, hi, lo);
          ((u16*)o1)[idx] = hi;
          ((u16*)o2)[idx] = lo;
        } else {
          ((float*)o1)[idx] = v;
        }
      }
    }
  }
}

// ---------------- LSTM scan: 1 workgroup (1024 thr) per batch element ----
// thread (col=t&255, kq=t>>8) owns the K-QUARTER [kq*64, kq*64+64) of gate
// rows col (i), 256+col (f), 512+col (g) in VGPRs: 3 gates x 8 uint4 = 96
// VGPRs of weights — fits the 128-VGPR cap the compiler grants 1024-thread
// blocks. o-gate rows in LDS chunk-transposed [kp4][col] (0 bank conflicts
// measured). h carried as fp16 hi+lo pair (fp32-grade). K-quarter partials
// reduced via 12 KB LDS. kq is wave-uniform -> divergence-free.
__global__ __launch_bounds__(1024) void lstm_k(const float* __restrict__ pre,
    const float* __restrict__ mask, const float* __restrict__ h0,
    const float* __restrict__ c0, const u16* __restrict__ whh,
    float* __restrict__ hs) {
  __shared__ __align__(16) uint4 lds_o[32 * 256];   // [kp4][col], 128 KB
  __shared__ __align__(16) float4 lds_red[3 * 256]; // kq=1..3 partials, 12 KB
  __shared__ __align__(16) u32 lds_hh[128];         // h hi (fp16 pairs)
  __shared__ __align__(16) u32 lds_hl[128];         // h lo
  const int t = threadIdx.x, b = blockIdx.x;
  const int col = t & 255, kq = t >> 8;             // kq wave-uniform
  uint4 wi[8], wf[8], wg[8];
  {
    const u32* wb = (const u32*)whh;
    const uint4* pi_ = (const uint4*)(wb + (u64)col * 128) + kq * 8;
    const uint4* pf_ = (const uint4*)(wb + (u64)(256 + col) * 128) + kq * 8;
    const uint4* pg_ = (const uint4*)(wb + (u64)(512 + col) * 128) + kq * 8;
    #pragma unroll
    for (int q = 0; q < 8; ++q) {
      wi[q] = pi_[q]; wf[q] = pf_[q]; wg[q] = pg_[q];
    }
    const uint4* po_ = (const uint4*)(wb + (u64)(768 + col) * 128);
    #pragma unroll
    for (int j = 0; j < 8; ++j) {
      const int kp4 = kq * 8 + j;
      lds_o[kp4 * 256 + col] = po_[kp4];
    }
  }
  float c = 0.f;
  if (kq == 0) c = c0[b * 256 + col];
  if (t < 128) {
    float a0 = h0[b * 256 + 2 * t], a1 = h0[b * 256 + 2 * t + 1];
    u16 h0a = f2h(a0); u16 l0a = f2h(a0 - h2f(h0a));
    u16 h1a = f2h(a1); u16 l1a = f2h(a1 - h2f(h1a));
    lds_hh[t] = (u32)h0a | ((u32)h1a << 16);
    lds_hl[t] = (u32)l0a | ((u32)l1a << 16);
  }
  float npi = 0.f, npf = 0.f, npg = 0.f, npo = 0.f;
  if (kq == 0) {                                    // prefetch step-0 pre
    const float* pr = pre + (u64)b * 1024;
    npi = pr[col]; npf = pr[256 + col]; npg = pr[512 + col]; npo = pr[768 + col];
  }
  __syncthreads();
  for (int s = 0; s < 80; ++s) {
    float ai = npi, afv = npf, ag = npg, ao = npo;  // kq!=0: zeros (partials)
    #pragma unroll
    for (int j = 0; j < 8; ++j) {
      const int kk = kq * 8 + j;
      const uint4 ov = lds_o[kk * 256 + col];       // conflict-free
      const uint4 hh = ((const uint4*)lds_hh)[kk];  // broadcast
      const uint4 hl = ((const uint4*)lds_hl)[kk];  // broadcast
      ai  = fdot2u(wi[j].x, hh.x, ai);  ai  = fdot2u(wi[j].y, hh.y, ai);
      ai  = fdot2u(wi[j].z, hh.z, ai);  ai  = fdot2u(wi[j].w, hh.w, ai);
      ai  = fdot2u(wi[j].x, hl.x, ai);  ai  = fdot2u(wi[j].y, hl.y, ai);
      ai  = fdot2u(wi[j].z, hl.z, ai);  ai  = fdot2u(wi[j].w, hl.w, ai);
      afv = fdot2u(wf[j].x, hh.x, afv); afv = fdot2u(wf[j].y, hh.y, afv);
      afv = fdot2u(wf[j].z, hh.z, afv); afv = fdot2u(wf[j].w, hh.w, afv);
      afv = fdot2u(wf[j].x, hl.x, afv); afv = fdot2u(wf[j].y, hl.y, afv);
      afv = fdot2u(wf[j].z, hl.z, afv); afv = fdot2u(wf[j].w, hl.w, afv);
      ag  = fdot2u(wg[j].x, hh.x, ag);  ag  = fdot2u(wg[j].y, hh.y, ag);
      ag  = fdot2u(wg[j].z, hh.z, ag);  ag  = fdot2u(wg[j].w, hh.w, ag);
      ag  = fdot2u(wg[j].x, hl.x, ag);  ag  = fdot2u(wg[j].y, hl.y, ag);
      ag  = fdot2u(wg[j].z, hl.z, ag);  ag  = fdot2u(wg[j].w, hl.w, ag);
      ao  = fdot2u(ov.x, hh.x, ao);     ao  = fdot2u(ov.y, hh.y, ao);
      ao  = fdot2u(ov.z, hh.z, ao);     ao  = fdot2u(ov.w, hh.w, ao);
      ao  = fdot2u(ov.x, hl.x, ao);     ao  = fdot2u(ov.y, hl.y, ao);
      ao  = fdot2u(ov.z, hl.z, ao);     ao  = fdot2u(ov.w, hl.w, ao);
    }
    if (kq != 0) {
      float4 r; r.x = ai; r.y = afv; r.z = ag; r.w = ao;
      lds_red[(kq - 1) * 256 + col] = r;
    } else if (s + 1 < 80) {                        // prefetch next-step pre
      const float* pr = pre + (u64)((s + 1) * 128 + b) * 1024;
      npi = pr[col]; npf = pr[256 + col]; npg = pr[512 + col]; npo = pr[768 + col];
    }
    __syncthreads();
    if (kq == 0) {
      const float4 r1 = lds_red[col];
      const float4 r2 = lds_red[256 + col];
      const float4 r3 = lds_red[512 + col];
      ai += r1.x + r2.x + r3.x;
      afv += r1.y + r2.y + r3.y;
      ag += r1.z + r2.z + r3.z;
      ao += r1.w + r2.w + r3.w;
      const float m = mask[s * 128 + b];
      const float ig = sigm(ai), fg = sigm(afv), og = sigm(ao);
      const float gg = tanhf(ag);
      const float cn = fg * c + ig * gg;
      const float hn = og * tanhf(cn);
      hs[(u64)(s * 128 + b) * 256 + col] = hn;      // unmasked output
      c = cn * m;
      const float hm = hn * m;                      // masked carry
      u16 hhi = f2h(hm);
      u16 hlo = f2h(hm - h2f(hhi));
      ((u16*)lds_hh)[col] = hhi;
      ((u16*)lds_hl)[col] = hlo;
    }
    __syncthreads();
  }
}

// ---------------- heads: value, log-softmax, entropy, action gather -------
__global__ __launch_bounds__(256) void heads_k(const float* __restrict__ hs,
    const float* __restrict__ vw, const float* __restrict__ vb,
    const float* __restrict__ lw, const float* __restrict__ lb,
    const int* __restrict__ acts, float* __restrict__ out) {
  const int lane = threadIdx.x & 63, wid = threadIdx.x >> 6;
  const int row = blockIdx.x * 4 + wid;
  const float4 h4 = *(const float4*)(hs + (u64)row * 256 + lane * 4);
  float lj[18];
  #pragma unroll
  for (int j = 0; j < 18; ++j) {
    const float4 w4 = *(const float4*)(lw + j * 256 + lane * 4);
    float p = h4.x * w4.x + h4.y * w4.y + h4.z * w4.z + h4.w * w4.w;
    #pragma unroll
    for (int o = 32; o > 0; o >>= 1) p += __shfl_xor(p, o, 64);
    lj[j] = p + lb[j];
  }
  const float4 v4 = *(const float4*)(vw + lane * 4);
  float val = h4.x * v4.x + h4.y * v4.y + h4.z * v4.z + h4.w * v4.w;
  #pragma unroll
  for (int o = 32; o > 0; o >>= 1) val += __shfl_xor(val, o, 64);
  val += vb[0];
  float mx = lj[0];
  #pragma unroll
  for (int j = 1; j < 18; ++j) mx = fmaxf(mx, lj[j]);
  float sum = 0.f;
  #pragma unroll
  for (int j = 0; j < 18; ++j) sum += __expf(lj[j] - mx);
  const float ls = __logf(sum);
  const int a = acts[row];
  float tlp = 0.f, ent = 0.f;
  #pragma unroll
  for (int j = 0; j < 18; ++j) {
    const float lp = lj[j] - mx - ls;
    const float pj = __expf(lp);
    ent -= pj * lp;
    if (j == a) tlp = lp;
  }
  if (lane == 0) {
    out[row]         = tlp;
    out[10240 + row] = ent;
    out[20480 + row] = val;
  }
}

// ---------------- launch ----------------
extern "C" void kernel_launch(void* const* d_in, const int* in_sizes, int n_in,
                              void* d_out, int out_size, void* d_ws, size_t ws_size,
                              hipStream_t stream) {
  const float* obs  = (const float*)d_in[0];
  const float* mask = (const float*)d_in[1];
  const float* h0   = (const float*)d_in[2];
  const float* c0   = (const float*)d_in[3];
  const int*   acts = (const int*)d_in[4];
  const float* w1   = (const float*)d_in[5];
  const float* b1   = (const float*)d_in[6];
  const float* w2   = (const float*)d_in[7];
  const float* b2   = (const float*)d_in[8];
  const float* fcw  = (const float*)d_in[9];
  const float* fcb  = (const float*)d_in[10];
  const float* wih  = (const float*)d_in[11];
  const float* whh  = (const float*)d_in[12];
  const float* bih  = (const float*)d_in[13];
  const float* bhh  = (const float*)d_in[14];
  const float* vw   = (const float*)d_in[15];
  const float* vb   = (const float*)d_in[16];
  const float* lw   = (const float*)d_in[17];
  const float* lb   = (const float*)d_in[18];
  float* out = (float*)d_out;

  char* cur = (char*)d_ws;
  auto carve = [&](size_t bytes) {
    void* p = cur; cur += (bytes + 255) & ~(size_t)255; return p;
  };
  u16*   out2h = (u16*)carve(10240ULL * 2592 * 2);
  u16*   out2l = (u16*)carve(10240ULL * 2592 * 2);
  u16*   xh    = (u16*)carve(10240ULL * 256 * 2);
  u16*   xl    = (u16*)carve(10240ULL * 256 * 2);
  float* pre   = (float*)carve(10240ULL * 1024 * 4);
  float* hs    = (float*)carve(10240ULL * 256 * 4);
  u16*   w1h   = (u16*)carve(4096ULL * 2);
  u16*   w1l   = (u16*)carve(4096ULL * 2);
  u16*   w2h   = (u16*)carve(8192ULL * 2);
  u16*   w2l   = (u16*)carve(8192ULL * 2);
  u16*   fwh   = (u16*)carve(663552ULL * 2);
  u16*   fwl   = (u16*)carve(663552ULL * 2);
  u16*   iwh   = (u16*)carve(262144ULL * 2);
  u16*   iwl   = (u16*)carve(262144ULL * 2);
  u16*   whhh  = (u16*)carve(262144ULL * 2);
  float* bsum  = (float*)carve(1024ULL * 4);

  prep_k<<<512, 256, 0, stream>>>(w1, w2, fcw, wih, whh, bih, bhh,
                                  w1h, w1l, w2h, w2l, fwh, fwl, iwh, iwl, whhh, bsum);
  conv_k<<<10240, 256, 0, stream>>>(obs, w1h, w1l, b1, w2h, w2l, b2, out2h, out2l);
  gemm3_k<1, 1><<<160, 256, 0, stream>>>(out2h, out2l, fwh, fwl, fcb, xh, xl,
                                         10240, 256, 2592);
  gemm3_k<0, 0><<<640, 256, 0, stream>>>(xh, xl, iwh, iwl, bsum, pre, nullptr,
                                         10240, 1024, 256);
  lstm_k<<<128, 1024, 0, stream>>>(pre, mask, h0, c0, whhh, hs);
  heads_k<<<2560, 256, 0, stream>>>(hs, vw, vb, lw, lb, acts, out);
}